// Round 10
// baseline (480.223 us; speedup 1.0000x reference)
//
#include <hip/hip_runtime.h>
#include <math.h>

// DCT2net, R10: R9 composite + circular-ring unroll-by-13 + Wr ring dropped.
//
// K2 (dct2net_k2): per 16-lane group (13 kj used), one patch column.
//   61-output-row segments (8 segs x 32 colchunks x 2 img = 512 blocks):
//     hDCT (x via ds_bpermute from 16 loader lanes, pre-scaled by 1/(3s))
//       -> circular buffer Rv[13], write slot k%13 (compile-time via unroll)
//     vDCT + shrink (even/odd symmetry; vDCT result IS u) -> tn[13], pnz
//     w = 1/(1+sum nz) via 4-step __shfl_xor butterfly in the 16-group
//     raw w stored per patch row (jj==0); duplicate writes across segment
//       overlap are bitwise identical (benign race)
//     fold (scaled by w) -> circular accumulator Hacc[13], slot (k+dx+2)%13
//     retire slot (k+2)%13: row a = hs+k-24 -> Hg[img][jj][a][col]; zero slot
//   Main loop: groups of 13 steps, fully unrolled -> all ring indices static,
//   zero shift-movs. NO __syncthreads in the loop; no cross-wave traffic.
// K3 (dct2net_k3): one out row per wave, 52 out cols/wave (lanes 52..63 halo).
//   13 coalesced H-plane loads; U[dy] = sum_jj c1[dy][jj] H[jj] (169 reg-FMA);
//   den = 13 coalesced w-row loads summed vertically (R7-proven), then 13-tap
//   horizontal sum via LDS. out = 3*sigma * num / den. No barriers.
//
// ws: Hg = 2 img x 13 jj x 488 x 512 f32 (26.0 MB), Wg = 2 x 500 x 512 (2.05 MB).

#define P13   13
#define IMGW  512
#define OUTW  488
#define SEGH  61       // 8*61 = 488 exact
#define NSEG  8
#define PLANE ((size_t)OUTW * IMGW)
#define WROWS 500

struct C1mat { float v[P13 * P13]; };  // v[x*13+k] = sqrt(2/13)*Ci[k]*cos((2x+1)k*pi/26)

__global__ __launch_bounds__(256) void dct2net_k2(
    const float* __restrict__ xg, const float* __restrict__ sigmag,
    float* __restrict__ Hg, float* __restrict__ Wg, C1mat c1)
{
    __shared__ float c1lds[169];
    const int tid = threadIdx.x;
    if (tid < 169) c1lds[tid] = c1.v[tid];
    __syncthreads();                       // once, for the c1 table only

    const int lane = tid & 63;
    const int wv   = tid >> 6;             // wave 0..3
    const int g    = lane >> 4;            // col group 0..3 within wave
    const int jj   = lane & 15;            // kj (0..12 used, 13..15 idle)
    const int img  = blockIdx.z;
    const int hs   = blockIdx.y * SEGH;    // first H row of this segment
    const int cbw  = blockIdx.x * 16 + wv * 4;   // wave's first col
    const int col  = cbw + g;              // this lane's patch column (0..511)

    const float inv3s = 1.0f / (3.0f * sigmag[0]);
    const float* xin  = xg + (size_t)img * IMGW * IMGW;

    const int jc = (jj < P13) ? jj : 12;
    float c1col[P13];
#pragma unroll
    for (int y = 0; y < P13; ++y) c1col[y] = c1lds[y * P13 + jc];

    float Rv[P13], Hacc[P13];
#pragma unroll
    for (int q = 0; q < P13; ++q) { Rv[q] = 0.0f; Hacc[q] = 0.0f; }

    int xcol = cbw + lane; xcol = (xcol < IMGW - 1) ? xcol : (IMGW - 1);
    float xv = 0.0f;
    if (lane < 16) xv = xin[(size_t)hs * IMGW + xcol] * inv3s;

    // ---- priming: k = 0..11, hDCT only, Rv slot = k (compile-time) ----
#pragma unroll
    for (int k = 0; k < 12; ++k) {
        float xw[P13];
#pragma unroll
        for (int y = 0; y < P13; ++y)
            xw[y] = __int_as_float(
                __builtin_amdgcn_ds_bpermute(4 * (g + y), __float_as_int(xv)));
        if (lane < 16)                      // hs+12 <= 439 < 512: no clamp needed
            xv = xin[(size_t)(hs + k + 1) * IMGW + xcol] * inv3s;
        float a0 = c1col[0] * xw[0], a1 = c1col[1] * xw[1];
#pragma unroll
        for (int y = 2; y < P13; y += 2) a0 = fmaf(c1col[y], xw[y], a0);
#pragma unroll
        for (int y = 3; y < P13; y += 2) a1 = fmaf(c1col[y], xw[y], a1);
        Rv[k] = a0 + a1;
    }

    // ---- main: k = 12..84 in groups of 13; all ring indices compile-time ----
    // write slot = k%13 = (12+s)%13;  positional R(x) = Rv[(s+x)%13];
    // fold slot(dx) = (s+dx+1)%13;    retire slot = (s+1)%13.
#pragma unroll 1
    for (int kb = 12; kb <= 84; kb += 13) {
#pragma unroll
        for (int s = 0; s < 13; ++s) {
            const int k = kb + s;
            if (k <= 84) {
                // gather sliding window from the 16 staged lanes
                float xw[P13];
#pragma unroll
                for (int y = 0; y < P13; ++y)
                    xw[y] = __int_as_float(
                        __builtin_amdgcn_ds_bpermute(4 * (g + y), __float_as_int(xv)));
                {   // prefetch next row (consumed next step)
                    int nr = hs + k + 1; nr = (nr < IMGW) ? nr : (IMGW - 1);
                    if (lane < 16) xv = xin[(size_t)nr * IMGW + xcol] * inv3s;
                }
                // hDCT -> circular slot
                float a0 = c1col[0] * xw[0], a1 = c1col[1] * xw[1];
#pragma unroll
                for (int y = 2; y < P13; y += 2) a0 = fmaf(c1col[y], xw[y], a0);
#pragma unroll
                for (int y = 3; y < P13; y += 2) a1 = fmaf(c1col[y], xw[y], a1);
                Rv[(12 + s) % 13] = a0 + a1;

                // vDCT (positional via circular reads) + shrink
                float Se[6], So[6];
#pragma unroll
                for (int t = 0; t < 6; ++t) {
                    const float rl = Rv[(s + t) % 13];
                    const float rh = Rv[(s + 12 - t) % 13];
                    Se[t] = rl + rh; So[t] = rl - rh;
                }
                const float r6 = Rv[(s + 6) % 13];
                float tn[P13]; float pnz = 0.0f;
#pragma unroll
                for (int i = 0; i < P13; ++i) {
                    float u;
                    if ((i & 1) == 0) {
                        u = c1.v[6 * P13 + i] * r6;
#pragma unroll
                        for (int t = 0; t < 6; ++t) u = fmaf(c1.v[t * P13 + i], Se[t], u);
                    } else {
                        u = c1.v[0 * P13 + i] * So[0];
#pragma unroll
                        for (int t = 1; t < 6; ++t) u = fmaf(c1.v[t * P13 + i], So[t], u);
                    }
                    float uc = __builtin_amdgcn_fmed3f(u, -1.3f, 1.3f);  // u^64<=2e7
                    float p2 = uc * uc, p4 = p2 * p2, p8 = p4 * p4;
                    float p16 = p8 * p8, p32 = p16 * p16, p64 = p32 * p32;
                    float nz = p64 * __builtin_amdgcn_rcpf(p64 + 1.0f);
                    pnz += nz;
                    tn[i] = u * nz;        // (t/(3s))*nz; K3 scales num by 3s
                }
                if (jj >= P13) pnz = 0.0f;
                pnz += __shfl_xor(pnz, 1, 16);
                pnz += __shfl_xor(pnz, 2, 16);
                pnz += __shfl_xor(pnz, 4, 16);
                pnz += __shfl_xor(pnz, 8, 16);
                const float w = __builtin_amdgcn_rcpf(1.0f + pnz);
                if (jj == 0)
                    Wg[((size_t)img * WROWS + (hs + k - 12)) * IMGW + col] = w;

                // fold (scaled by w) into circular accumulator
#pragma unroll
                for (int i = 0; i < P13; ++i) tn[i] *= w;
#pragma unroll
                for (int dx = 0; dx < 6; ++dx) {
                    float E = c1.v[dx * P13 + 0] * tn[0];
#pragma unroll
                    for (int i = 2; i < P13; i += 2) E = fmaf(c1.v[dx * P13 + i], tn[i], E);
                    float O = c1.v[dx * P13 + 1] * tn[1];
#pragma unroll
                    for (int i = 3; i < P13; i += 2) O = fmaf(c1.v[dx * P13 + i], tn[i], O);
                    Hacc[(s + dx + 1) % 13]  += E + O;
                    Hacc[(s + 13 - dx) % 13] += E - O;
                }
                {
                    float z6 = c1.v[6 * P13 + 0] * tn[0];
#pragma unroll
                    for (int i = 2; i < P13; i += 2) z6 = fmaf(c1.v[6 * P13 + i], tn[i], z6);
                    Hacc[(s + 7) % 13] += z6;
                }

                // retire slot (s+1)%13 = output row hs+k-24; then zero it
                if (k >= 24) {
                    const int a = hs + k - 24;      // in [hs, hs+60] <= 487
                    if (jj < P13)
                        Hg[(size_t)(img * P13 + jj) * PLANE + (size_t)a * IMGW + col]
                            = Hacc[(s + 1) % 13];
                }
                Hacc[(s + 1) % 13] = 0.0f;
            }
        }
    }
}

__global__ __launch_bounds__(256) void dct2net_k3(
    const float* __restrict__ Hg, const float* __restrict__ Wg,
    const float* __restrict__ sigmag, float* __restrict__ outg, C1mat c1)
{
    // R9-proven body; divisor now from 13 coalesced raw-w row loads (R7-proven).
    __shared__ float U[4][80][14];   // stride 14: 2-way bank alias only (free)
    __shared__ float vw[4][80];
    const int tid  = threadIdx.x;
    const int lane = tid & 63;
    const int wv   = tid >> 6;
    const int img  = blockIdx.z;
    const int a    = blockIdx.y * 4 + wv;      // out row (< 488)
    const int cb   = blockIdx.x * 52;          // out col base

    int c = cb + lane; c = (c <= 499) ? c : 499;   // clamp; clamped slots masked

    // 13 coalesced plane loads for this out row
    float hv[P13];
    const float* hbase = Hg + (size_t)img * P13 * PLANE + (size_t)a * IMGW + c;
#pragma unroll
    for (int jj = 0; jj < P13; ++jj) hv[jj] = hbase[jj * PLANE];

    // U[dy] = sum_jj c1[dy][jj] * hv[jj]  (169 reg-FMA, c1 scalar operands)
#pragma unroll
    for (int dy = 0; dy < P13; ++dy) {
        float s0 = c1.v[dy * P13 + 0] * hv[0];
        float s1 = c1.v[dy * P13 + 1] * hv[1];
#pragma unroll
        for (int j = 2; j < P13; j += 2) s0 = fmaf(c1.v[dy * P13 + j], hv[j], s0);
#pragma unroll
        for (int j = 3; j < P13; j += 2) s1 = fmaf(c1.v[dy * P13 + j], hv[j], s1);
        U[wv][lane][dy] = s0 + s1;
    }
    // vertical 13-sum of raw w (coalesced row loads, rows a..a+12 <= 499)
    {
        const float* wp = Wg + ((size_t)img * WROWS + a) * IMGW + c;
        float sw = 0.0f;
#pragma unroll
        for (int dx = 0; dx < P13; ++dx) sw += wp[(size_t)dx * IMGW];
        vw[wv][lane] = sw;
    }

    // same-wave LDS write->read: program order, no barrier needed
    float num = 0.0f;
#pragma unroll
    for (int dy = 0; dy < P13; ++dy) num += U[wv][lane + 12 - dy][dy];
    float den = 0.0f;
#pragma unroll
    for (int d = 0; d < P13; ++d) den += vw[wv][lane + d];

    const int b = cb + lane;
    if (lane < 52 && b < OUTW)
        outg[((size_t)img * OUTW + a) * OUTW + b] =
            num * (3.0f * sigmag[0]) * __builtin_amdgcn_rcpf(den);
}

extern "C" void kernel_launch(void* const* d_in, const int* in_sizes, int n_in,
                              void* d_out, int out_size, void* d_ws, size_t ws_size,
                              hipStream_t stream)
{
    const float* x     = (const float*)d_in[0];
    const float* sigma = (const float*)d_in[1];
    float* out = (float*)d_out;

    C1mat c1;
    const double PI = 3.14159265358979323846;
    for (int xx = 0; xx < 13; ++xx)
        for (int k = 0; k < 13; ++k) {
            double Ci = (k == 0) ? (1.0 / sqrt(2.0)) : 1.0;
            c1.v[xx * 13 + k] =
                (float)(sqrt(2.0 / 13.0) * Ci * cos((2 * xx + 1) * k * PI / 26.0));
        }

    float* Hg = (float*)d_ws;                    // 2*13*488*512 f32 = 26.0 MB
    float* Wg = Hg + (size_t)2 * P13 * PLANE;    // 2*500*512 f32   =  2.05 MB

    dct2net_k2<<<dim3(32, NSEG, 2), 256, 0, stream>>>(x, sigma, Hg, Wg, c1);
    dct2net_k3<<<dim3(10, 122, 2), 256, 0, stream>>>(Hg, Wg, sigma, out, c1);
}